// Round 2
// baseline (326.724 us; speedup 1.0000x reference)
//
#include <hip/hip_runtime.h>
#include <hip/hip_bf16.h>

#define BN   8
#define NN   1024
#define CIN  256
#define COUT 256
#define HH   4
#define CC   64
#define ALPHA_C 0.2f
#define NEG_INF_C (-9000000000000000.0f)

#define ROWS_K1 16
#define ITILE 16
#define JTILE 64

// ---------------- Kernel 1: h = X@W^T + b, plus transposed l_src/l_dst ----------------
__global__ __launch_bounds__(256) void k1_gemm(
    const float* __restrict__ X, const float* __restrict__ W,
    const float* __restrict__ bias, const float* __restrict__ a,
    float* __restrict__ h, float* __restrict__ lsrc_t, float* __restrict__ ldst_t)
{
    __shared__ float4 Xs4[ROWS_K1 * 64];   // 16 rows x 256 f32 = 16 KB

    const int row0 = blockIdx.x * ROWS_K1;
    const int b    = row0 >> 10;           // batch (16 | 1024, no straddle)
    const float4* X4 = (const float4*)(X + (size_t)row0 * CIN);
    for (int v = threadIdx.x; v < ROWS_K1 * 64; v += 256) Xs4[v] = X4[v];
    __syncthreads();

    const int c = threadIdx.x;                    // output channel 0..255
    const float4* W4 = (const float4*)(W + (size_t)c * CIN);

    float acc[ROWS_K1];
    #pragma unroll
    for (int i = 0; i < ROWS_K1; ++i) acc[i] = 0.f;

    for (int k4 = 0; k4 < 64; ++k4) {
        float4 w4 = W4[k4];
        #pragma unroll
        for (int i = 0; i < ROWS_K1; ++i) {
            float4 x4 = Xs4[i * 64 + k4];        // broadcast
            acc[i] += x4.x * w4.x + x4.y * w4.y + x4.z * w4.z + x4.w * w4.w;
        }
    }

    const float bv = bias[c];
    const int hh = c >> 6, cc = c & 63;
    const float asrc = a[hh * (2 * CC) + cc];
    const float adst = a[hh * (2 * CC) + CC + cc];
    const int lane = threadIdx.x & 63;

    #pragma unroll
    for (int i = 0; i < ROWS_K1; ++i) {
        float v = acc[i] + bv;
        h[(size_t)(row0 + i) * COUT + c] = v;
        float s1 = v * asrc, s2 = v * adst;
        #pragma unroll
        for (int off = 32; off >= 1; off >>= 1) {
            s1 += __shfl_xor(s1, off);
            s2 += __shfl_xor(s2, off);
        }
        if (lane == 0) {
            int i_in = (row0 + i) & 1023;
            lsrc_t[((size_t)b * HH + hh) * NN + i_in] = s1;
            ldst_t[((size_t)b * HH + hh) * NN + i_in] = s2;
        }
    }
}

// ---------------- Kernel 2: masked softmax attention + PV (no online softmax) --------
// Phase 1 mapping: wave = head hw, lane = jl (tile-local j)
// Phase 2 mapping: wave w owns il-quad w (il=4w..4w+3); lane c4 = channel-quad
__global__ __launch_bounds__(256) void k2_attn(
    const float* __restrict__ h, const int* __restrict__ adj,
    const float* __restrict__ lsrc_t, const float* __restrict__ ldst_t,
    float* __restrict__ out)
{
    __shared__ float4 p_s[2][JTILE * 16];      // [buf][jj*16 + h*4 + swz(quad)]  32 KB
    __shared__ float  lsum_s[ITILE * HH];

    const int bidx = blockIdx.x;
    const int b  = bidx >> 6;                  // 64 i-tiles per batch
    const int i0 = (bidx & 63) * ITILE;
    const int tid = threadIdx.x;
    const int hw = tid >> 6;                   // head (= phase-2 wave w)
    const int jl = tid & 63;                   // lane (= phase-2 c4)
    const int hd2 = jl >> 4;                   // phase-2 head (from channel-quad)

    const float* ldst_b = ldst_t + ((size_t)b * HH + hw) * NN;
    const float* lsrc_b = lsrc_t + ((size_t)b * HH + hw) * NN + i0;

    // ---- phase 0: M = max over ALL j of ldst (valid softmax shift via monotonicity)
    float mx = -3.4e38f;
    #pragma unroll
    for (int jt = 0; jt < 16; ++jt) mx = fmaxf(mx, ldst_b[jt * 64 + jl]);
    #pragma unroll
    for (int off = 32; off >= 1; off >>= 1) mx = fmaxf(mx, __shfl_xor(mx, off));

    float lsrc_r[ITILE], m_r[ITILE], lsum[ITILE];
    #pragma unroll
    for (int il = 0; il < ITILE; ++il) {
        lsrc_r[il] = lsrc_b[il];
        float t = lsrc_r[il] + mx;
        m_r[il] = (t > 0.f) ? t : ALPHA_C * t;   // guaranteed >= every masked logit
        lsum[il] = 0.f;
    }

    float4 acc0 = make_float4(0,0,0,0), acc1 = acc0, acc2 = acc0, acc3 = acc0;

    const int*   adjp = adj + ((size_t)b * NN + i0) * NN;
    const float* h_b  = h   + (size_t)b * NN * COUT;

    for (int t = 0; t < NN / JTILE; ++t) {
        const int j0 = t * JTILE;
        const int buf = t & 1;
        const float ldv = ldst_b[j0 + jl];
        const int* adj_p = adjp + j0 + jl;

        // ---- phase 1: p = exp(lrelu(lsrc+ldst) - m) masked, per-lane sum ----
        #pragma unroll
        for (int q = 0; q < 4; ++q) {
            float4 pj4;
            {
                const int il = 4*q+0;
                int av = adj_p[(size_t)il * NN];
                float s = lsrc_r[il] + ldv; s = (s > 0.f) ? s : ALPHA_C * s;
                float pj = __expf(s - m_r[il]); pj = av ? pj : 0.f;
                lsum[il] += pj; pj4.x = pj;
            }
            {
                const int il = 4*q+1;
                int av = adj_p[(size_t)il * NN];
                float s = lsrc_r[il] + ldv; s = (s > 0.f) ? s : ALPHA_C * s;
                float pj = __expf(s - m_r[il]); pj = av ? pj : 0.f;
                lsum[il] += pj; pj4.y = pj;
            }
            {
                const int il = 4*q+2;
                int av = adj_p[(size_t)il * NN];
                float s = lsrc_r[il] + ldv; s = (s > 0.f) ? s : ALPHA_C * s;
                float pj = __expf(s - m_r[il]); pj = av ? pj : 0.f;
                lsum[il] += pj; pj4.z = pj;
            }
            {
                const int il = 4*q+3;
                int av = adj_p[(size_t)il * NN];
                float s = lsrc_r[il] + ldv; s = (s > 0.f) ? s : ALPHA_C * s;
                float pj = __expf(s - m_r[il]); pj = av ? pj : 0.f;
                lsum[il] += pj; pj4.w = pj;
            }
            p_s[buf][jl * 16 + hw * 4 + (q ^ (jl & 3))] = pj4;
        }
        __syncthreads();

        // ---- phase 2: acc[q] += p[il=4w+q] * h[j][:] ----
        #pragma unroll 8
        for (int jj = 0; jj < JTILE; ++jj) {
            float4 hv = ((const float4*)(h_b + (size_t)(j0 + jj) * COUT))[jl];
            float4 pv = p_s[buf][jj * 16 + hd2 * 4 + (hw ^ (jj & 3))];
            acc0.x += pv.x * hv.x; acc0.y += pv.x * hv.y; acc0.z += pv.x * hv.z; acc0.w += pv.x * hv.w;
            acc1.x += pv.y * hv.x; acc1.y += pv.y * hv.y; acc1.z += pv.y * hv.z; acc1.w += pv.y * hv.w;
            acc2.x += pv.z * hv.x; acc2.y += pv.z * hv.y; acc2.z += pv.z * hv.z; acc2.w += pv.z * hv.w;
            acc3.x += pv.w * hv.x; acc3.y += pv.w * hv.y; acc3.z += pv.w * hv.z; acc3.w += pv.w * hv.w;
        }
        // double-buffered p_s: next tile writes the other buffer; the barrier
        // at tile t+1 (post-write) guarantees all waves finished tile-t reads
        // before tile t+2 overwrites this buffer.
    }

    // ---- final: reduce per-lane sums across the 64 j-lanes ----
    #pragma unroll
    for (int il = 0; il < ITILE; ++il) {
        float s = lsum[il];
        #pragma unroll
        for (int off = 32; off >= 1; off >>= 1) s += __shfl_xor(s, off);
        if (jl == 0) lsum_s[il * HH + hw] = s;
    }
    __syncthreads();

    {
        float inv0 = 1.0f / lsum_s[(4*hw+0) * HH + hd2];
        float inv1 = 1.0f / lsum_s[(4*hw+1) * HH + hd2];
        float inv2 = 1.0f / lsum_s[(4*hw+2) * HH + hd2];
        float inv3 = 1.0f / lsum_s[(4*hw+3) * HH + hd2];
        float4 o0 = make_float4(acc0.x*inv0, acc0.y*inv0, acc0.z*inv0, acc0.w*inv0);
        float4 o1 = make_float4(acc1.x*inv1, acc1.y*inv1, acc1.z*inv1, acc1.w*inv1);
        float4 o2 = make_float4(acc2.x*inv2, acc2.y*inv2, acc2.z*inv2, acc2.w*inv2);
        float4 o3 = make_float4(acc3.x*inv3, acc3.y*inv3, acc3.z*inv3, acc3.w*inv3);
        ((float4*)(out + (size_t)(b * NN + i0 + 4*hw + 0) * COUT))[jl] = o0;
        ((float4*)(out + (size_t)(b * NN + i0 + 4*hw + 1) * COUT))[jl] = o1;
        ((float4*)(out + (size_t)(b * NN + i0 + 4*hw + 2) * COUT))[jl] = o2;
        ((float4*)(out + (size_t)(b * NN + i0 + 4*hw + 3) * COUT))[jl] = o3;
    }
}

extern "C" void kernel_launch(void* const* d_in, const int* in_sizes, int n_in,
                              void* d_out, int out_size, void* d_ws, size_t ws_size,
                              hipStream_t stream) {
    const float* X    = (const float*)d_in[0];
    const int*   adj  = (const int*)  d_in[1];
    const float* W    = (const float*)d_in[2];
    const float* bias = (const float*)d_in[3];
    const float* a    = (const float*)d_in[4];
    float* out = (float*)d_out;

    float* h      = (float*)d_ws;                        // B*N*COUT f32 = 8 MB
    float* lsrc_t = h      + (size_t)BN * NN * COUT;     // [b][h][n]
    float* ldst_t = lsrc_t + (size_t)BN * HH * NN;       // [b][h][n]

    k1_gemm<<<(BN * NN) / ROWS_K1, 256, 0, stream>>>(X, W, bias, a, h, lsrc_t, ldst_t);
    k2_attn<<<BN * (NN / ITILE), 256, 0, stream>>>(h, adj, lsrc_t, ldst_t, out);
}

// Round 3
// 113.537 us; speedup vs baseline: 2.8777x; 2.8777x over previous
//
#include <hip/hip_runtime.h>
#include <hip/hip_bf16.h>

#define BN   8
#define NN   1024
#define CIN  256
#define COUT 256
#define HH   4
#define CC   64
#define ALPHA_C 0.2f

#define ROWS_K1 16
#define ITILE 16
#define JT 32           // j-tile rows staged in LDS
#define NT (NN / JT)    // 32 tiles

__device__ __forceinline__ void gl_lds16(const void* g, void* l) {
    __builtin_amdgcn_global_load_lds(
        (const __attribute__((address_space(1))) void*)g,
        (__attribute__((address_space(3))) void*)l, 16, 0, 0);
}

// ---------------- Kernel 1: h = X@W^T + b (bf16 out), transposed l_src/l_dst ----------
__global__ __launch_bounds__(256) void k1_gemm(
    const float* __restrict__ X, const float* __restrict__ W,
    const float* __restrict__ bias, const float* __restrict__ a,
    unsigned short* __restrict__ hbf, float* __restrict__ lsrc_t, float* __restrict__ ldst_t)
{
    __shared__ float4 Xs4[ROWS_K1 * 64];   // 16 rows x 256 f32 = 16 KB

    const int row0 = blockIdx.x * ROWS_K1;
    const int b    = row0 >> 10;
    const float4* X4 = (const float4*)(X + (size_t)row0 * CIN);
    for (int v = threadIdx.x; v < ROWS_K1 * 64; v += 256) Xs4[v] = X4[v];
    __syncthreads();

    const int c = threadIdx.x;
    const float4* W4 = (const float4*)(W + (size_t)c * CIN);

    float acc[ROWS_K1];
    #pragma unroll
    for (int i = 0; i < ROWS_K1; ++i) acc[i] = 0.f;

    for (int k4 = 0; k4 < 64; ++k4) {
        float4 w4 = W4[k4];
        #pragma unroll
        for (int i = 0; i < ROWS_K1; ++i) {
            float4 x4 = Xs4[i * 64 + k4];
            acc[i] += x4.x * w4.x + x4.y * w4.y + x4.z * w4.z + x4.w * w4.w;
        }
    }

    const float bv = bias[c];
    const int hh = c >> 6, cc = c & 63;
    const float asrc = a[hh * (2 * CC) + cc];
    const float adst = a[hh * (2 * CC) + CC + cc];
    const int lane = threadIdx.x & 63;

    #pragma unroll
    for (int i = 0; i < ROWS_K1; ++i) {
        float v = acc[i] + bv;
        __hip_bfloat16 hv = __float2bfloat16(v);
        hbf[(size_t)(row0 + i) * COUT + c] = *(unsigned short*)&hv;
        float s1 = v * asrc, s2 = v * adst;
        #pragma unroll
        for (int off = 32; off >= 1; off >>= 1) {
            s1 += __shfl_xor(s1, off);
            s2 += __shfl_xor(s2, off);
        }
        if (lane == 0) {
            int i_in = (row0 + i) & 1023;
            lsrc_t[((size_t)b * HH + hh) * NN + i_in] = s1;
            ldst_t[((size_t)b * HH + hh) * NN + i_in] = s2;
        }
    }
}

// ---------------- Kernel 2: masked softmax attention + PV ----------------------------
// XCD swizzle: b = bid&7 -> one batch per XCD (h + adj stay in local L2).
// Phase 1: wave = head, lane = (ihalf, jl in 0..31); 8 il's per lane.
// Phase 2: wave wv owns jj = 8wv..8wv+7; lane = channel-quad; acc[16] partials, LDS-reduced.
__global__ __launch_bounds__(256) void k2_attn(
    const unsigned short* __restrict__ hbf, const int* __restrict__ adj,
    const float* __restrict__ lsrc_t, const float* __restrict__ ldst_t,
    float* __restrict__ out)
{
    __shared__ __align__(16) uint4  shbuf[1024];        // 16 KB: h-tile (bf16), later acc-reduce
    __shared__ __align__(16) float  p_lds[JT][HH][16];  // 8 KB, XOR-swizzled il
    __shared__ float lsum_s[ITILE * HH];

    const int bid = blockIdx.x;
    const int b   = bid & 7;
    const int i0  = (bid >> 3) * ITILE;
    const int tid = threadIdx.x;
    const int wv  = tid >> 6;
    const int ln  = tid & 63;
    const int ihalf = ln >> 5;
    const int jl  = ln & 31;
    const int hd2 = ln >> 4;          // phase-2 head from channel-quad

    const float* ldst_b = ldst_t + ((size_t)b * HH + wv) * NN;
    const float* lsrc_b = lsrc_t + ((size_t)b * HH + wv) * NN + i0;

    // phase 0: mx = max_j ldst (per head) -> valid softmax shift via lrelu monotonicity
    float mx = -3.4e38f;
    #pragma unroll
    for (int jt = 0; jt < 16; ++jt) mx = fmaxf(mx, ldst_b[jt * 64 + ln]);
    #pragma unroll
    for (int off = 32; off >= 1; off >>= 1) mx = fmaxf(mx, __shfl_xor(mx, off));

    float lsrc_r[8], m_r[8], lsum[8];
    #pragma unroll
    for (int q = 0; q < 8; ++q) {
        lsrc_r[q] = lsrc_b[ihalf * 8 + q];
        float t = lsrc_r[q] + mx;
        m_r[q] = (t > 0.f) ? t : ALPHA_C * t;
        lsum[q] = 0.f;
    }

    float4 acc[16];
    #pragma unroll
    for (int i = 0; i < 16; ++i) acc[i] = make_float4(0.f, 0.f, 0.f, 0.f);

    const int* adjp = adj + ((size_t)b * NN + i0) * NN + jl;
    const unsigned short* hsrc = hbf + (size_t)b * NN * COUT;
    unsigned short* hs = (unsigned short*)shbuf;

    int a_cur[8], a_nxt[8];
    float ldv_cur, ldv_nxt;
    #pragma unroll
    for (int q = 0; q < 8; ++q) a_cur[q] = adjp[(size_t)(ihalf * 8 + q) * NN];
    ldv_cur = ldst_b[jl];

    for (int t = 0; t < NT; ++t) {
        __syncthreads();                       // A: prev phase-2 done reading hs & p_lds
        // ---- stage h tile t (32 rows x 256 bf16 = 16 KB) via global_load_lds ----
        {
            const unsigned short* src = hsrc + (size_t)(t * JT) * COUT;
            #pragma unroll
            for (int k = 0; k < 4; ++k) {
                int chunk = wv * 4 + k;                    // 64 float4's per chunk
                gl_lds16(src + (size_t)(chunk * 64 + ln) * 8, hs + (size_t)chunk * 512);
            }
        }
        // ---- phase 1: p = exp(lrelu(lsrc+ldst) - m) masked ----
        #pragma unroll
        for (int q = 0; q < 8; ++q) {
            int il = ihalf * 8 + q;
            float s = lsrc_r[q] + ldv_cur;
            s = (s > 0.f) ? s : ALPHA_C * s;
            float pj = __expf(s - m_r[q]);
            pj = a_cur[q] ? pj : 0.f;
            lsum[q] += pj;
            p_lds[jl][wv][il ^ (jl & 15)] = pj;
        }
        __syncthreads();                       // B: hs staged (vmcnt drained) + p written
        // ---- prefetch adj/ldst for tile t+1 (lands during phase 2) ----
        {
            int tn = (t + 1 < NT) ? t + 1 : t;
            #pragma unroll
            for (int q = 0; q < 8; ++q) a_nxt[q] = adjp[(size_t)(ihalf * 8 + q) * NN + tn * JT];
            ldv_nxt = ldst_b[tn * JT + jl];
        }
        // ---- phase 2: wave wv handles jj = 8wv..8wv+7, all 16 il ----
        {
            const uint2*  hs2 = (const uint2*)hs;
            const float4* p4  = (const float4*)p_lds;
            #pragma unroll
            for (int j8 = 0; j8 < 8; ++j8) {
                const int jj = wv * 8 + j8;
                uint2 hraw = hs2[jj * 64 + ln];
                float h0 = __uint_as_float(hraw.x << 16);
                float h1 = __uint_as_float(hraw.x & 0xffff0000u);
                float h2 = __uint_as_float(hraw.y << 16);
                float h3 = __uint_as_float(hraw.y & 0xffff0000u);
                const int jq = (jj >> 2) & 3;              // runtime: address only
                float4 pv0 = p4[jj * 16 + hd2 * 4 + (0 ^ jq)];
                float4 pv1 = p4[jj * 16 + hd2 * 4 + (1 ^ jq)];
                float4 pv2 = p4[jj * 16 + hd2 * 4 + (2 ^ jq)];
                float4 pv3 = p4[jj * 16 + hd2 * 4 + (3 ^ jq)];
                #define KAP (j8 & 3)                        // == jj&3, static after unroll
                #define FMA4(A, P) { (A).x += (P)*h0; (A).y += (P)*h1; (A).z += (P)*h2; (A).w += (P)*h3; }
                FMA4(acc[0*4 + (0^KAP)], pv0.x); FMA4(acc[0*4 + (1^KAP)], pv0.y);
                FMA4(acc[0*4 + (2^KAP)], pv0.z); FMA4(acc[0*4 + (3^KAP)], pv0.w);
                FMA4(acc[1*4 + (0^KAP)], pv1.x); FMA4(acc[1*4 + (1^KAP)], pv1.y);
                FMA4(acc[1*4 + (2^KAP)], pv1.z); FMA4(acc[1*4 + (3^KAP)], pv1.w);
                FMA4(acc[2*4 + (0^KAP)], pv2.x); FMA4(acc[2*4 + (1^KAP)], pv2.y);
                FMA4(acc[2*4 + (2^KAP)], pv2.z); FMA4(acc[2*4 + (3^KAP)], pv2.w);
                FMA4(acc[3*4 + (0^KAP)], pv3.x); FMA4(acc[3*4 + (1^KAP)], pv3.y);
                FMA4(acc[3*4 + (2^KAP)], pv3.z); FMA4(acc[3*4 + (3^KAP)], pv3.w);
                #undef KAP
            }
        }
        #pragma unroll
        for (int q = 0; q < 8; ++q) a_cur[q] = a_nxt[q];
        ldv_cur = ldv_nxt;
    }

    // ---- lsum reduce over the 32 j-lanes (offsets <=16 stay within each half) ----
    #pragma unroll
    for (int q = 0; q < 8; ++q) {
        float s = lsum[q];
        #pragma unroll
        for (int off = 16; off >= 1; off >>= 1) s += __shfl_xor(s, off);
        lsum[q] = s;
    }
    if (jl == 0) {
        #pragma unroll
        for (int q = 0; q < 8; ++q) lsum_s[(ihalf * 8 + q) * HH + wv] = lsum[q];
    }
    __syncthreads();                           // also: everyone done with hs -> reuse as red

    // ---- cross-wave acc reduction in LDS (reuse shbuf as float4 red[16][64]) ----
    float4* red = (float4*)shbuf;
    #pragma unroll
    for (int w = 0; w < 4; ++w) {
        if (wv == w) {
            #pragma unroll
            for (int i = 0; i < 16; ++i) {
                int idx = i * 64 + ln;
                if (w == 0) red[idx] = acc[i];
                else {
                    float4 r = red[idx];
                    r.x += acc[i].x; r.y += acc[i].y; r.z += acc[i].z; r.w += acc[i].w;
                    red[idx] = r;
                }
            }
        }
        __syncthreads();
    }

    // ---- epilogue: divide by lsum, write out ----
    float4* out4 = (float4*)(out + ((size_t)b * NN + i0) * COUT);
    #pragma unroll
    for (int r = 0; r < 4; ++r) {
        int fi = r * 256 + tid;
        int il = fi >> 6, c4 = fi & 63;
        int hd = c4 >> 4;
        float inv = 1.0f / lsum_s[il * HH + hd];
        float4 v = red[fi];
        v.x *= inv; v.y *= inv; v.z *= inv; v.w *= inv;
        out4[(size_t)il * 64 + c4] = v;
    }
}

extern "C" void kernel_launch(void* const* d_in, const int* in_sizes, int n_in,
                              void* d_out, int out_size, void* d_ws, size_t ws_size,
                              hipStream_t stream) {
    const float* X    = (const float*)d_in[0];
    const int*   adj  = (const int*)  d_in[1];
    const float* W    = (const float*)d_in[2];
    const float* bias = (const float*)d_in[3];
    const float* a    = (const float*)d_in[4];
    float* out = (float*)d_out;

    unsigned short* hbf = (unsigned short*)d_ws;                    // B*N*COUT bf16 = 4 MB
    float* lsrc_t = (float*)(hbf + (size_t)BN * NN * COUT);         // [b][h][n] f32
    float* ldst_t = lsrc_t + (size_t)BN * HH * NN;

    k1_gemm<<<(BN * NN) / ROWS_K1, 256, 0, stream>>>(X, W, bias, a, hbf, lsrc_t, ldst_t);
    k2_attn<<<BN * (NN / ITILE), 256, 0, stream>>>(hbf, adj, lsrc_t, ldst_t, out);
}

// Round 5
// 99.286 us; speedup vs baseline: 3.2907x; 1.1435x over previous
//
#include <hip/hip_runtime.h>
#include <hip/hip_bf16.h>

#define BN   8
#define NN   1024
#define CIN  256
#define COUT 256
#define HH   4
#define CC   64
#define ALPHA_C 0.2f

#define ROWS_K1 8

typedef __attribute__((ext_vector_type(8))) short short8;
typedef __attribute__((ext_vector_type(4))) float f32x4;

__device__ __forceinline__ unsigned short f2bf(float x) {
    __hip_bfloat16 h = __float2bfloat16(x);
    return *(unsigned short*)&h;
}

// ---------------- Kernel 1: h = X@W^T + b -> hbf_t[b][c][j] (bf16, transposed), l_src/l_dst
__global__ __launch_bounds__(256) void k1_gemm(
    const float* __restrict__ X, const float* __restrict__ W,
    const float* __restrict__ bias, const float* __restrict__ a,
    unsigned short* __restrict__ hbf_t, float* __restrict__ lsrc_t, float* __restrict__ ldst_t)
{
    __shared__ float4 Xs4[ROWS_K1 * 64];   // 8 rows x 256 f32 = 8 KB

    const int row0 = blockIdx.x * ROWS_K1;
    const int b    = row0 >> 10;
    const int j0   = row0 & 1023;          // within-batch row (the fix: don't add b*1024 twice)
    const float4* X4 = (const float4*)(X + (size_t)row0 * CIN);
    for (int v = threadIdx.x; v < ROWS_K1 * 64; v += 256) Xs4[v] = X4[v];
    __syncthreads();

    const int c = threadIdx.x;
    const float4* W4 = (const float4*)(W + (size_t)c * CIN);

    float acc[ROWS_K1];
    #pragma unroll
    for (int i = 0; i < ROWS_K1; ++i) acc[i] = 0.f;

    #pragma unroll 4
    for (int k4 = 0; k4 < 64; ++k4) {
        float4 w4 = W4[k4];
        #pragma unroll
        for (int i = 0; i < ROWS_K1; ++i) {
            float4 x4 = Xs4[i * 64 + k4];
            acc[i] += x4.x * w4.x + x4.y * w4.y + x4.z * w4.z + x4.w * w4.w;
        }
    }

    const float bv = bias[c];
    const int hh = c >> 6, cc = c & 63;
    const float asrc = a[hh * (2 * CC) + cc];
    const float adst = a[hh * (2 * CC) + CC + cc];
    const int lane = threadIdx.x & 63;

    unsigned short us[ROWS_K1];
    #pragma unroll
    for (int i = 0; i < ROWS_K1; ++i) {
        float v = acc[i] + bv;
        us[i] = f2bf(v);
        float s1 = v * asrc, s2 = v * adst;
        #pragma unroll
        for (int off = 32; off >= 1; off >>= 1) {
            s1 += __shfl_xor(s1, off);
            s2 += __shfl_xor(s2, off);
        }
        if (lane == 0) {
            lsrc_t[((size_t)b * HH + hh) * NN + (j0 + i)] = s1;
            ldst_t[((size_t)b * HH + hh) * NN + (j0 + i)] = s2;
        }
    }
    // 8 bf16 = 16 B contiguous along j (j0 % 8 == 0 -> 16B aligned)
    *(uint4*)(hbf_t + ((size_t)(b * 256 + c) << 10) + j0) = *(uint4*)us;
}

// ---------------- Kernel 2: masked softmax attention, PV via MFMA -------------------
// grid 512, 256 thr. b = bid&7 (one batch per XCD). wave = head. No LDS, no barriers.
// Lane l: A-row il = l&15, k-group jg = l>>4 (k = 8*jg+e). B-col = l&15.
// C/D: col = l&15, row = 4*jg + reg  (m89-verified layout).
__global__ __launch_bounds__(256) void k2_attn(
    const unsigned short* __restrict__ hbf_t, const int* __restrict__ adj,
    const float* __restrict__ lsrc_t, const float* __restrict__ ldst_t,
    float* __restrict__ out)
{
    const int bid = blockIdx.x;
    const int b   = bid & 7;
    const int i0  = (bid >> 3) * 16;
    const int tid = threadIdx.x;
    const int h   = tid >> 6;
    const int l   = tid & 63;
    const int il  = l & 15;
    const int jg  = l >> 4;

    const float* ldst_b = ldst_t + ((size_t)b * HH + h) * NN;
    const float* lsrc_b = lsrc_t + ((size_t)b * HH + h) * NN + i0;

    // phase 0: mx = max_j ldst (valid softmax shift: lrelu is monotone)
    float mx = -3.4e38f;
    #pragma unroll
    for (int jt = 0; jt < 16; ++jt) mx = fmaxf(mx, ldst_b[jt * 64 + l]);
    #pragma unroll
    for (int off = 32; off >= 1; off >>= 1) mx = fmaxf(mx, __shfl_xor(mx, off));

    const float lsrc_v = lsrc_b[il];
    float t0 = lsrc_v + mx;
    const float m_r = (t0 > 0.f) ? t0 : ALPHA_C * t0;
    float lsum = 0.f;

    // pointers for this lane
    const int*   adj_r = adj + ((size_t)b * NN + i0 + il) * NN + jg * 8;
    const float* ld_r  = ldst_b + jg * 8;
    const short8* bp0 = (const short8*)(hbf_t + ((size_t)(b * 256 + h * 64 + 0 * 16 + il) << 10));
    const short8* bp1 = (const short8*)(hbf_t + ((size_t)(b * 256 + h * 64 + 1 * 16 + il) << 10));
    const short8* bp2 = (const short8*)(hbf_t + ((size_t)(b * 256 + h * 64 + 2 * 16 + il) << 10));
    const short8* bp3 = (const short8*)(hbf_t + ((size_t)(b * 256 + h * 64 + 3 * 16 + il) << 10));

    f32x4 acc0 = {0.f,0.f,0.f,0.f}, acc1 = acc0, acc2 = acc0, acc3 = acc0;

    // preload tile 0
    int4   aA = *(const int4*)(adj_r);
    int4   aB = *(const int4*)(adj_r + 4);
    float4 dA = *(const float4*)(ld_r);
    float4 dB = *(const float4*)(ld_r + 4);
    short8 b0 = bp0[jg], b1 = bp1[jg], b2 = bp2[jg], b3 = bp3[jg];

    #pragma unroll 2
    for (int t = 0; t < 32; ++t) {
        // ---- prefetch tile t+1 (independent; overlaps exp+MFMA below) ----
        const int tn = (t < 31) ? t + 1 : 31;
        int4   aAn = *(const int4*)(adj_r + tn * 32);
        int4   aBn = *(const int4*)(adj_r + tn * 32 + 4);
        float4 dAn = *(const float4*)(ld_r + tn * 32);
        float4 dBn = *(const float4*)(ld_r + tn * 32 + 4);
        short8 b0n = bp0[tn * 4 + jg], b1n = bp1[tn * 4 + jg];
        short8 b2n = bp2[tn * 4 + jg], b3n = bp3[tn * 4 + jg];

        // ---- phase 1: p = exp(lrelu(lsrc+ldst) - m) masked -> A-frag ----
        short8 af;
        {
            const int*   av = (const int*)&aA;
            const float* dv = (const float*)&dA;
            #pragma unroll
            for (int e = 0; e < 4; ++e) {
                float s = lsrc_v + dv[e];
                s = (s > 0.f) ? s : ALPHA_C * s;
                float p = __expf(s - m_r);
                p = av[e] ? p : 0.f;
                lsum += p;
                af[e] = (short)f2bf(p);
            }
        }
        {
            const int*   av = (const int*)&aB;
            const float* dv = (const float*)&dB;
            #pragma unroll
            for (int e = 0; e < 4; ++e) {
                float s = lsrc_v + dv[e];
                s = (s > 0.f) ? s : ALPHA_C * s;
                float p = __expf(s - m_r);
                p = av[e] ? p : 0.f;
                lsum += p;
                af[4 + e] = (short)f2bf(p);
            }
        }

        // ---- phase 2: 4 MFMAs (N-subtiles of 16 cols) ----
        acc0 = __builtin_amdgcn_mfma_f32_16x16x32_bf16(af, b0, acc0, 0, 0, 0);
        acc1 = __builtin_amdgcn_mfma_f32_16x16x32_bf16(af, b1, acc1, 0, 0, 0);
        acc2 = __builtin_amdgcn_mfma_f32_16x16x32_bf16(af, b2, acc2, 0, 0, 0);
        acc3 = __builtin_amdgcn_mfma_f32_16x16x32_bf16(af, b3, acc3, 0, 0, 0);

        aA = aAn; aB = aBn; dA = dAn; dB = dBn;
        b0 = b0n; b1 = b1n; b2 = b2n; b3 = b3n;
    }

    // ---- lsum: reduce across the 4 k-groups; lane x then holds lsum for il = x&15
    lsum += __shfl_xor(lsum, 16);
    lsum += __shfl_xor(lsum, 32);

    float inv[4];
    #pragma unroll
    for (int r = 0; r < 4; ++r) inv[r] = 1.0f / __shfl(lsum, 4 * jg + r);

    float* outp = out + ((size_t)b * NN + i0) * COUT + h * 64 + il;
    #pragma unroll
    for (int r = 0; r < 4; ++r) {
        const size_t ro = (size_t)(4 * jg + r) * COUT;
        outp[ro +  0] = acc0[r] * inv[r];
        outp[ro + 16] = acc1[r] * inv[r];
        outp[ro + 32] = acc2[r] * inv[r];
        outp[ro + 48] = acc3[r] * inv[r];
    }
}

extern "C" void kernel_launch(void* const* d_in, const int* in_sizes, int n_in,
                              void* d_out, int out_size, void* d_ws, size_t ws_size,
                              hipStream_t stream) {
    const float* X    = (const float*)d_in[0];
    const int*   adj  = (const int*)  d_in[1];
    const float* W    = (const float*)d_in[2];
    const float* bias = (const float*)d_in[3];
    const float* a    = (const float*)d_in[4];
    float* out = (float*)d_out;

    unsigned short* hbf_t = (unsigned short*)d_ws;                  // [b][c][j] bf16, 4 MB
    float* lsrc_t = (float*)(hbf_t + (size_t)BN * COUT * NN);       // [b][h][n] f32
    float* ldst_t = lsrc_t + (size_t)BN * HH * NN;

    k1_gemm<<<(BN * NN) / ROWS_K1, 256, 0, stream>>>(X, W, bias, a, hbf_t, lsrc_t, ldst_t);
    k2_attn<<<BN * (NN / 16), 256, 0, stream>>>(hbf_t, adj, lsrc_t, ldst_t, out);
}